// Round 1
// baseline (679.111 us; speedup 1.0000x reference)
//
#include <hip/hip_runtime.h>
#include <hip/hip_bf16.h>

typedef __attribute__((ext_vector_type(8))) short short8;
typedef __attribute__((ext_vector_type(4))) float floatx4;
typedef unsigned short u16;
typedef unsigned int u32;

#define D 128          // IN == OUT == 128
#define TM 32          // rows per tile (fp32 in LDS -> smaller tile)
#define NT 8           // tiles per block chunk
#define CHUNK (TM*NT)  // 256 rows per block

static __device__ __forceinline__ u16 f2bf(float f) {
  union { float f; u32 u; } v; v.f = f;
  u32 r = v.u + 0x7fffu + ((v.u >> 16) & 1u);   // RNE round to bf16
  return (u16)(r >> 16);
}

// v_cvt_pk_bf16_f32 via library pair-convert (compiler lowers this well; m240)
static __device__ __forceinline__ u32 pk2(float x, float y) {
  union { __hip_bfloat162 h; u32 u; } c;
  c.h = __float22bfloat162_rn(make_float2(x, y));
  return c.u;
}

union S8u { short8 s; u32 u[4]; };

// ---------------- prep: zero S, build W1^T in bf16 ----------------
__global__ void prep_kernel(const float* __restrict__ W1, u16* __restrict__ W1T,
                            float* __restrict__ S, int nS)
{
  int t = blockIdx.x * blockDim.x + threadIdx.x;
  if (t < D * D) {
    int k = t >> 7;          // W1 row (input dim)
    int n = t & (D - 1);     // W1 col (output dim)
    W1T[n * D + k] = f2bf(W1[t]);
  }
  if (t < nS) S[t] = 0.f;
}

// ---------------- main: g = relu(x@W1+b1), segment-sum into S ----------------
// Block: 256 threads (4 waves). Wave w owns output cols [32w, 32w+32).
// x-tile staged fp32 via global_load_lds (HBM->LDS DMA, no VGPR round trip).
// LDS layout XOR-swizzled at 16B-granule level: phys_g = (g&24) | ((g^row)&7).
//  - write side: linear LDS dest (DMA requirement) + pre-swizzled GLOBAL src addr
//  - read side : same XOR on ds_read_b128 address  (guide rule #21: both sides)
// fp32->bf16 conversion happens at read (v_cvt_pk), right before MFMA.
__global__ __launch_bounds__(256, 4)
void fused_mlp_segsum(const float* __restrict__ x1,
                      const int* __restrict__ slices,
                      const u16* __restrict__ W1T,
                      const float* __restrict__ b1,
                      float* __restrict__ S,
                      int E, int B)
{
  __shared__ __align__(16) float xt[2][TM * D];   // 2 * 16 KiB

  const int tid  = threadIdx.x;
  const int wv   = tid >> 6;
  const int lane = tid & 63;
  const int quad = lane >> 4;
  const int l16  = lane & 15;

  const int chunkStart = blockIdx.x * CHUNK;
  const int chunkEnd   = min(chunkStart + CHUNK, E);
  const int ntiles     = (chunkEnd - chunkStart + TM - 1) / TM;

  // --- B fragments (W1^T) into registers: ct = 2*wv + c ---
  // lane(quad,l16) holds W1T[ct*16+l16][kk*32+quad*8 .. +7]
  short8 bf[2][4];
  #pragma unroll
  for (int c = 0; c < 2; ++c)
    #pragma unroll
    for (int kk = 0; kk < 4; ++kk)
      bf[c][kk] = *(const short8*)(W1T + ((2 * wv + c) * 16 + l16) * D + kk * 32 + quad * 8);

  float bias[2] = { b1[wv * 32 + l16], b1[wv * 32 + 16 + l16] };

  // --- ds_read float indices (swizzled). row&7 == l16&7, so per-thread constant.
  // A-frag floats [0..3] at logical granule kk*8+quad*2, [4..7] at +1.
  const int idxA = l16 * D + ((( quad * 2     ) ^ (l16 & 7)) << 2);
  const int idxB = l16 * D + (((quad * 2 + 1) ^ (l16 & 7)) << 2);

  // --- staging lane constants: flat granule f = wv*256 + i*64 + lane ---
  const int pg  = lane & 31;    // phys granule within row
  const int rhi = lane >> 5;    // row parity within call

  auto stage = [&](float* buf, int rowBase) {
    #pragma unroll
    for (int i = 0; i < 4; ++i) {
      int rs = wv * 8 + i * 2 + rhi;                 // row within tile
      int lg = (pg & 24) | ((pg ^ rs) & 7);          // logical granule for this phys slot
      int grow = min(rowBase + rs, E - 1);           // tail clamp (excess rows masked in seg logic)
      const float* src = x1 + (size_t)grow * D + lg * 4;
      float* dst = buf + rs * D + pg * 4;            // == buf + f*4  (linear in lane order)
      __builtin_amdgcn_global_load_lds(
          (const __attribute__((address_space(1))) void*)src,
          (__attribute__((address_space(3))) void*)dst, 16, 0, 0);
    }
  };

  // --- current segment: last s with slices[s] <= chunkStart; cache boundaries ---
  int l = 0, r = B + 1;
  while (l < r) { int m = (l + r) >> 1; if (slices[m] <= chunkStart) l = m + 1; else r = m; }
  int cur = l - 1;
  int curStart = slices[cur];
  int nextEnd  = slices[cur + 1];
  float racc0 = 0.f, racc1 = 0.f;

  // --- prologue: stage tile 0 ---
  stage(xt[0], chunkStart);
  __syncthreads();   // compiler drains vmcnt(0) here -> tile 0 resident

  for (int t = 0; t < ntiles; ++t) {
    const int base = chunkStart + t * TM;

    // ---- issue DMA for tile t+1 into the other buffer (lands during compute) ----
    if (t + 1 < ntiles) stage(xt[(t + 1) & 1], base + TM);

    // ---- MFMA on buffer t&1: read fp32 (swizzled), cvt_pk -> bf16 frags ----
    const float* xb = xt[t & 1];
    floatx4 acc[2][2];
    #pragma unroll
    for (int rt = 0; rt < 2; ++rt)
      #pragma unroll
      for (int c = 0; c < 2; ++c)
        acc[rt][c] = (floatx4){0.f, 0.f, 0.f, 0.f};

    #pragma unroll
    for (int kk = 0; kk < 4; ++kk) {
      #pragma unroll
      for (int rt = 0; rt < 2; ++rt) {
        float4 fa = *(const float4*)(xb + idxA + rt * 2048 + kk * 32);
        float4 fb = *(const float4*)(xb + idxB + rt * 2048 + kk * 32);
        S8u a;
        a.u[0] = pk2(fa.x, fa.y); a.u[1] = pk2(fa.z, fa.w);
        a.u[2] = pk2(fb.x, fb.y); a.u[3] = pk2(fb.z, fb.w);
        acc[rt][0] = __builtin_amdgcn_mfma_f32_16x16x32_bf16(a.s, bf[0][kk], acc[rt][0], 0, 0, 0);
        acc[rt][1] = __builtin_amdgcn_mfma_f32_16x16x32_bf16(a.s, bf[1][kk], acc[rt][1], 0, 0, 0);
      }
    }

    // ---- bias + relu; C layout: row(in 16-tile) = quad*4+i, col = ct*16+l16 ----
    #pragma unroll
    for (int rt = 0; rt < 2; ++rt)
      #pragma unroll
      for (int c = 0; c < 2; ++c)
        #pragma unroll
        for (int i = 0; i < 4; ++i)
          acc[rt][c][i] = fmaxf(acc[rt][c][i] + bias[c], 0.f);

    // ---- segment reduction over this tile's rows ----
    const int tileHi = min(base + TM, chunkEnd);

    auto segAdd = [&](int loR, int hiR) {   // tile-relative row range [loR,hiR)
      #pragma unroll
      for (int rt = 0; rt < 2; ++rt)
        #pragma unroll
        for (int i = 0; i < 4; ++i) {
          int rowOff = rt * 16 + quad * 4 + i;
          bool in = (rowOff >= loR) && (rowOff < hiR);
          racc0 += in ? acc[rt][0][i] : 0.f;
          racc1 += in ? acc[rt][1][i] : 0.f;
        }
    };
    auto flushSeg = [&](int s) {
      float t0 = racc0, t1 = racc1;
      t0 += __shfl_xor(t0, 16); t0 += __shfl_xor(t0, 32);
      t1 += __shfl_xor(t1, 16); t1 += __shfl_xor(t1, 32);
      if (quad == 0) {
        atomicAdd(&S[s * D + wv * 32 + l16], t0);
        atomicAdd(&S[s * D + wv * 32 + 16 + l16], t1);
      }
    };

    // segments ending within this tile (boundaries cached in registers)
    while (nextEnd <= tileHi) {
      int lo = max(curStart, base);
      if (nextEnd > lo) segAdd(lo - base, nextEnd - base);
      flushSeg(cur);
      racc0 = 0.f; racc1 = 0.f;
      curStart = nextEnd;
      ++cur;
      nextEnd = (cur < B) ? slices[cur + 1] : 0x7fffffff;
    }
    // segment continuing past this tile
    {
      int lo = max(curStart, base);
      if (lo < tileHi) {
        if (lo == base && tileHi == base + TM) {
          #pragma unroll
          for (int rt = 0; rt < 2; ++rt)
            #pragma unroll
            for (int i = 0; i < 4; ++i) { racc0 += acc[rt][0][i]; racc1 += acc[rt][1][i]; }
        } else {
          segAdd(lo - base, tileHi - base);
        }
      }
    }

    __syncthreads();   // drains vmcnt -> next buffer resident; also guards WAR on xt
  }

  // final flush for the segment spilling past chunkEnd
  if (cur < B && curStart < chunkEnd) {
    float t0 = racc0, t1 = racc1;
    t0 += __shfl_xor(t0, 16); t0 += __shfl_xor(t0, 32);
    t1 += __shfl_xor(t1, 16); t1 += __shfl_xor(t1, 32);
    if (quad == 0) {
      atomicAdd(&S[cur * D + wv * 32 + l16], t0);
      atomicAdd(&S[cur * D + wv * 32 + 16 + l16], t1);
    }
  }
}

// ---------------- finish: out = ((S/cnt)@W2+b2)@W3+b3 ; empty -> b3 ----------------
__global__ __launch_bounds__(128)
void finish_mlp(const float* __restrict__ S, const int* __restrict__ slices,
                const float* __restrict__ W2, const float* __restrict__ b2,
                const float* __restrict__ W3, const float* __restrict__ b3,
                float* __restrict__ out, int B)
{
  __shared__ float v0[D];
  __shared__ float v1[D];
  int s = blockIdx.x;
  int j = threadIdx.x;
  int c0 = slices[s], c1 = slices[s + 1];
  int cnt = c1 - c0;
  if (cnt <= 0) { out[s * D + j] = b3[j]; return; }   // uniform branch
  v0[j] = S[s * D + j] * (1.f / (float)cnt);
  __syncthreads();
  float a = b2[j];
  #pragma unroll 8
  for (int k = 0; k < D; ++k) a = fmaf(v0[k], W2[k * D + j], a);
  v1[j] = a;
  __syncthreads();
  float o = b3[j];
  #pragma unroll 8
  for (int k = 0; k < D; ++k) o = fmaf(v1[k], W3[k * D + j], o);
  out[s * D + j] = o;
}

extern "C" void kernel_launch(void* const* d_in, const int* in_sizes, int n_in,
                              void* d_out, int out_size, void* d_ws, size_t ws_size,
                              hipStream_t stream) {
  const float* x1     = (const float*)d_in[0];
  const int*   slices = (const int*)d_in[1];
  const float* W1     = (const float*)d_in[2];
  const float* b1     = (const float*)d_in[3];
  const float* W2     = (const float*)d_in[4];
  const float* b2     = (const float*)d_in[5];
  const float* W3     = (const float*)d_in[6];
  const float* b3     = (const float*)d_in[7];
  float* out = (float*)d_out;

  const int E = in_sizes[0] / D;
  const int B = in_sizes[1] - 1;

  float* S   = (float*)d_ws;                               // B*D f32
  u16*   W1T = (u16*)((char*)d_ws + (size_t)B * D * 4);    // D*D bf16

  int nS = B * D;
  prep_kernel<<<(nS + 255) / 256, 256, 0, stream>>>(W1, W1T, S, nS);

  int nblk = (E + CHUNK - 1) / CHUNK;
  fused_mlp_segsum<<<nblk, 256, 0, stream>>>(x1, slices, W1T, b1, S, E, B);

  finish_mlp<<<B, D, 0, stream>>>(S, slices, W2, b2, W3, b3, out, B);
}